// Round 11
// baseline (160.128 us; speedup 1.0000x reference)
//
#include <hip/hip_runtime.h>
#include <stdint.h>

#define N_ROWS 4096
#define N_DIM  2048
#define MARGIN 0.3f
#define NTILE  32            // 4096 / 128 tiles per side
#define NITER  (N_DIM / 64)  // BK=64 -> 32 K-iterations (even)
#define FLTMAX 3.402823466e+38f

typedef __attribute__((ext_vector_type(8))) short short8;
typedef __attribute__((ext_vector_type(4))) float floatx4;

// Packed layout ("fragment order"): for 16-row group b (256 total) and k-chunk
// c (32 k, 64 total), a 1 KB block at shorts-offset (b*64+c)*512. Lane l's
// 16 B fragment at l*8 shorts = row b*16+(l&15), k c*32+(l>>4)*8 (verified
// absmax 0.0 in R1-R10).

__device__ inline unsigned short f2bf_rne(float f) {
  unsigned u = __float_as_uint(f);
  unsigned r = 0x7fffu + ((u >> 16) & 1u);
  return (unsigned short)((u + r) >> 16);
}
__device__ inline float bf2f(unsigned short h) {
  return __uint_as_float(((unsigned)h) << 16);
}

// Barrier without the vmcnt(0) drain: LDS visibility needs only lgkmcnt(0);
// global loads (B prefetch, A staging for later iters) stay in flight.
__device__ inline void barrier_lds_only() {
  asm volatile("s_waitcnt lgkmcnt(0)" ::: "memory");
  __builtin_amdgcn_s_barrier();
}

// ---------------------------------------------------------------------------
// Kernel 1: cast fp32 -> bf16 AND repack into fragment order; sq[i] from the
// ROUNDED values; init per-row reduction cells. One block per 16-row group.
// ---------------------------------------------------------------------------
__global__ __launch_bounds__(256) void prep_kernel(
    const float* __restrict__ X, unsigned short* __restrict__ Xp,
    float* __restrict__ sq, unsigned* __restrict__ ap, unsigned* __restrict__ an)
{
  const int b = blockIdx.x;
  const int t = threadIdx.x;
  const int r = t & 15, j = (t >> 4) & 3, w = t >> 6;
  const float* Xg = X + ((size_t)b * 16 + r) * N_DIM + j * 8;
  unsigned short* Op = Xp + (size_t)b * 64 * 512 + (size_t)(j * 16 + r) * 8;
  float acc = 0.f;
#pragma unroll
  for (int s = 0; s < 16; ++s) {
    const int c = w + s * 4;
    float4 v0 = *(const float4*)(Xg + c * 32);
    float4 v1 = *(const float4*)(Xg + c * 32 + 4);
    short8 o;
    o[0] = (short)f2bf_rne(v0.x); o[1] = (short)f2bf_rne(v0.y);
    o[2] = (short)f2bf_rne(v0.z); o[3] = (short)f2bf_rne(v0.w);
    o[4] = (short)f2bf_rne(v1.x); o[5] = (short)f2bf_rne(v1.y);
    o[6] = (short)f2bf_rne(v1.z); o[7] = (short)f2bf_rne(v1.w);
#pragma unroll
    for (int e = 0; e < 8; ++e) {
      float f = bf2f((unsigned short)o[e]);
      acc = fmaf(f, f, acc);
    }
    *(short8*)(Op + (size_t)c * 512) = o;
  }
  acc += __shfl_xor(acc, 16, 64);
  acc += __shfl_xor(acc, 32, 64);
  __shared__ float part[4][16];
  if ((t & 63) < 16) part[w][r] = acc;
  __syncthreads();
  if (t < 16) {
    float s4 = part[0][t] + part[1][t] + part[2][t] + part[3][t];
    sq[b * 16 + t] = s4;
    ap[b * 16 + t] = 0u;           // max identity (dist >= 0)
    an[b * 16 + t] = 0x7f7fffffu;  // FLT_MAX bits
  }
}

// ---------------------------------------------------------------------------
// Kernel 2: upper-triangle 128x128 tiles, wave grid 1x4 (wave tile 32x128).
// A panel: LDS-staged (16 KB/iter, identity chunk map, conflict-free,
// double-buffered, lgkm-only barrier). B panel: every wave needs the SAME
// 8 fragments per kh -> loaded directly from packed global; the 4x
// within-block redundancy is deduped by L1 (waves barrier-synced). This cuts
// LDS traffic 96->32 KB per block-iter (R8/R10 were at the ~85 B/cyc ds_read
// ceiling) and L2 traffic to ~24 KB per 2.1 MFLOP. All pipeline register
// sets are NAMED variables (compile-time indices; R9 scratch lesson).
// Each wave's 32x128 output feeds row-side AND (symmetry) col-side
// hardest-pos/neg reductions.
// ---------------------------------------------------------------------------
__global__ __launch_bounds__(256, 2) void dist_kernel(
    const unsigned short* __restrict__ Xp, const float* __restrict__ sq,
    const int* __restrict__ lab, unsigned* __restrict__ ap, unsigned* __restrict__ an)
{
  __shared__ __align__(16) unsigned short As[2][8192];   // 2 x 16 KB (A only)
  __shared__ float sqi[128], sqj[128];
  __shared__ int labi[128], labj[128];

  // decode linear block id -> (bi, bj) with bi <= bj
  int p = blockIdx.x;
  int bi = 0;
  while (p >= NTILE - bi) { p -= NTILE - bi; ++bi; }
  const int bj = bi + p;

  const int t = threadIdx.x;
  const int lane = t & 63, w = t >> 6;     // wave w: rows [32w, 32w+32)

  if (t < 128) { int rr = bi * 128 + t; sqi[t] = sq[rr]; labi[t] = lab[rr]; }
  else         { int cc = bj * 128 + (t - 128); sqj[t - 128] = sq[cc]; labj[t - 128] = lab[cc]; }

  // A staging, identity chunk map: chunk c = q*256 + t (q<4, 16 B each).
  // LDS shorts offset c*8; global shorts: ((bi*8 + (c>>7))*64)*512 +
  // (c&127)*8 + it*1024.  (c&127)*8 == ((c>>6)&1)*512 + (c&63)*8, i.e. the
  // copy lands chunks exactly in slot (rg*2+kc)*512 + lane*8 fragment order.
  unsigned gA[4], lo[4];
#pragma unroll
  for (int q = 0; q < 4; ++q) {
    const unsigned c = q * 256 + t;
    gA[q] = ((unsigned)(bi * 8 + (c >> 7)) * 64) * 512 + (c & 127) * 8;
    lo[q] = c * 8;
  }
  // B fragment bases: frag (it,kh,ni) at bo[ni] + (2*it+kh)*512
  unsigned bo[8];
#pragma unroll
  for (int ni = 0; ni < 8; ++ni)
    bo[ni] = ((unsigned)(bj * 8 + ni) * 64) * 512 + lane * 8;

  short8 raA0[4], raA1[4];   // A staging ping-pong
  short8 bf0[8], bf1[8];     // B kh ping-pong

#define LOADA(RA, IT)                                                        \
  do {                                                                       \
    _Pragma("unroll")                                                        \
    for (int q = 0; q < 4; ++q)                                              \
      RA[q] = *(const short8*)(Xp + gA[q] + (unsigned)(IT) * 1024);          \
  } while (0)
#define STOREA(RA, BUF)                                                      \
  do {                                                                       \
    _Pragma("unroll")                                                        \
    for (int q = 0; q < 4; ++q)                                              \
      *(short8*)&As[BUF][lo[q]] = RA[q];                                     \
  } while (0)
#define LOADB(BF, IT, KH)                                                    \
  do {                                                                       \
    _Pragma("unroll")                                                        \
    for (int ni = 0; ni < 8; ++ni)                                           \
      BF[ni] = *(const short8*)(Xp + bo[ni] + (unsigned)(2 * (IT) + (KH)) * 512); \
  } while (0)
#define COMPUTE(BUF, KH, BF)                                                 \
  do {                                                                       \
    short8 af[2];                                                            \
    _Pragma("unroll")                                                        \
    for (int mi = 0; mi < 2; ++mi)                                           \
      af[mi] = *(const short8*)&As[BUF][((2 * w + mi) * 2 + (KH)) * 512 + lane * 8]; \
    _Pragma("unroll")                                                        \
    for (int mi = 0; mi < 2; ++mi)                                           \
      _Pragma("unroll")                                                      \
      for (int ni = 0; ni < 8; ++ni)                                         \
        acc[mi][ni] = __builtin_amdgcn_mfma_f32_16x16x32_bf16(               \
            af[mi], BF[ni], acc[mi][ni], 0, 0, 0);                           \
  } while (0)

  floatx4 acc[2][8] = {};

  // prologue: A(0)->buf0, B(0,kh0)->bf0, A(1) in flight in raA1
  LOADA(raA0, 0);
  STOREA(raA0, 0);
  LOADB(bf0, 0, 0);
  LOADA(raA1, 1);
  barrier_lds_only();

  for (int it = 0; it < NITER; it += 2) {
    // even sub-iter: compute buf0; raA1 holds A(it+1); bf0 holds B(it,0)
    if (it + 2 < NITER) LOADA(raA0, it + 2);
    LOADB(bf1, it, 1);
    COMPUTE(0, 0, bf0);
    LOADB(bf0, it + 1, 0);            // it+1 < NITER always here (NITER even)
    COMPUTE(0, 1, bf1);
    STOREA(raA1, 1);                  // A(it+1) -> buf1
    barrier_lds_only();
    // odd sub-iter: compute buf1; raA0 holds A(it+2); bf0 holds B(it+1,0)
    if (it + 3 < NITER) LOADA(raA1, it + 3);
    LOADB(bf1, it + 1, 1);
    COMPUTE(1, 0, bf0);
    if (it + 2 < NITER) LOADB(bf0, it + 2, 0);
    COMPUTE(1, 1, bf1);
    if (it + 2 < NITER) {
      STOREA(raA0, 0);                // A(it+2) -> buf0
      barrier_lds_only();
    }
  }
#undef LOADA
#undef STOREA
#undef LOADB
#undef COMPUTE

  // Epilogue. C/D layout (m89): col = lane&15, row = (lane>>4)*4 + reg.
  const int cn = lane & 15, lg = lane >> 4;
  float sqc[8]; int labc[8];
#pragma unroll
  for (int ni = 0; ni < 8; ++ni) {
    int c = ni * 16 + cn;
    sqc[ni] = sqj[c]; labc[ni] = labj[c];
  }
  float cap[8], can[8];
#pragma unroll
  for (int ni = 0; ni < 8; ++ni) { cap[ni] = 0.f; can[ni] = FLTMAX; }
#pragma unroll
  for (int mi = 0; mi < 2; ++mi) {
#pragma unroll
    for (int r = 0; r < 4; ++r) {
      const int rl = w * 32 + mi * 16 + lg * 4 + r;   // row within 128-tile
      const float si = sqi[rl];
      const int li = labi[rl];
      float apv = 0.0f;
      float anv = FLTMAX;
#pragma unroll
      for (int ni = 0; ni < 8; ++ni) {
        float g = acc[mi][ni][r];
        float d2 = fmaf(-2.0f, g, si + sqc[ni]);
        d2 = fmaxf(d2, 1e-12f);
        float d = __builtin_amdgcn_sqrtf(d2);
        const bool same = (li == labc[ni]);
        const float dp = same ? d : 0.0f;
        const float dn = same ? FLTMAX : d;
        apv = fmaxf(apv, dp);
        anv = fminf(anv, dn);
        cap[ni] = fmaxf(cap[ni], dp);   // col-side (symmetric) partials
        can[ni] = fminf(can[ni], dn);
      }
      // row side: reduce over the 16 cn-lanes (same lg = same row)
#pragma unroll
      for (int m = 8; m >= 1; m >>= 1) {
        apv = fmaxf(apv, __shfl_xor(apv, m, 64));
        anv = fminf(anv, __shfl_xor(anv, m, 64));
      }
      if (cn == 0) {
        int R = bi * 128 + rl;
        atomicMax(&ap[R], __float_as_uint(apv));
        atomicMin(&an[R], __float_as_uint(anv));
      }
    }
  }
  // col side: reduce over lg (xor 16,32) -> this wave's 32 rows per column
#pragma unroll
  for (int ni = 0; ni < 8; ++ni) {
    float a = cap[ni], b = can[ni];
#pragma unroll
    for (int m = 16; m <= 32; m <<= 1) {
      a = fmaxf(a, __shfl_xor(a, m, 64));
      b = fminf(b, __shfl_xor(b, m, 64));
    }
    if (lg == 0) {
      int C = bj * 128 + ni * 16 + cn;
      atomicMax(&ap[C], __float_as_uint(a));
      atomicMin(&an[C], __float_as_uint(b));
    }
  }
}

// ---------------------------------------------------------------------------
// Kernel 3: loss = mean(relu(margin + dist_ap - dist_an))
// ---------------------------------------------------------------------------
__global__ __launch_bounds__(256) void finalize_kernel(
    const unsigned* __restrict__ ap, const unsigned* __restrict__ an,
    float* __restrict__ out)
{
  const int t = threadIdx.x;
  float s = 0.f;
  for (int i = t; i < N_ROWS; i += 256) {
    float a = __uint_as_float(ap[i]);
    float b = __uint_as_float(an[i]);
    s += fmaxf(MARGIN + a - b, 0.0f);
  }
#pragma unroll
  for (int m = 32; m >= 1; m >>= 1) s += __shfl_down(s, m, 64);
  __shared__ float wsum[4];
  const int lane = t & 63, w = t >> 6;
  if (lane == 0) wsum[w] = s;
  __syncthreads();
  if (t == 0) out[0] = (wsum[0] + wsum[1] + wsum[2] + wsum[3]) * (1.0f / N_ROWS);
}

extern "C" void kernel_launch(void* const* d_in, const int* in_sizes, int n_in,
                              void* d_out, int out_size, void* d_ws, size_t ws_size,
                              hipStream_t stream) {
  const float* X = (const float*)d_in[0];
  const int* lab = (const int*)d_in[1];
  float* out = (float*)d_out;

  char* ws = (char*)d_ws;
  unsigned short* Xp = (unsigned short*)ws;                           // 16 MB packed
  float* sq  = (float*)(ws + (size_t)N_ROWS * N_DIM * 2);             // 16 KB
  unsigned* ap = (unsigned*)((char*)sq + N_ROWS * sizeof(float));     // 16 KB
  unsigned* an = (unsigned*)((char*)ap + N_ROWS * sizeof(unsigned));  // 16 KB

  prep_kernel<<<N_ROWS / 16, 256, 0, stream>>>(X, Xp, sq, ap, an);
  dist_kernel<<<NTILE * (NTILE + 1) / 2, 256, 0, stream>>>(Xp, sq, lab, ap, an);
  finalize_kernel<<<1, 256, 0, stream>>>(ap, an, out);
}